// Round 4
// baseline (561.782 us; speedup 1.0000x reference)
//
#include <hip/hip_runtime.h>
#include <stdint.h>

typedef __attribute__((ext_vector_type(8))) short s16x8;     // bf16 MFMA A/B frag (4 VGPRs)
typedef __attribute__((ext_vector_type(16))) float f32x16;   // 32x32 MFMA C/D frag
typedef __attribute__((ext_vector_type(4))) unsigned short us4;

// ---- bf16 round-to-nearest-even (inputs are finite normals) ----
__device__ inline unsigned short bf_rne(float f) {
    union { float f; uint32_t u; } v; v.f = f;
    uint32_t u = v.u;
    u += 0x7FFFu + ((u >> 16) & 1u);
    return (unsigned short)(u >> 16);
}

// async global->LDS, 16B per lane; LDS dst is wave-uniform base + lane*16
#define GLD_LDS16(gp, lp)                                                     \
    __builtin_amdgcn_global_load_lds(                                         \
        (const __attribute__((address_space(1))) void*)(gp),                  \
        (__attribute__((address_space(3))) void*)(lp), 16, 0, 0)

#define LGKM(n) asm volatile("s_waitcnt lgkmcnt(" #n ")" ::: "memory")
#define VMC(n)  asm volatile("s_waitcnt vmcnt(" #n ")" ::: "memory")
#define SFENCE() __builtin_amdgcn_sched_barrier(0)

// ---------------- prep: adapted = W + B@A -> bf16, scale = mag/rownorm ----------------
__global__ __launch_bounds__(256) void prep_kernel(
    const float4* __restrict__ W4,
    const float4* __restrict__ A4,   // [16][1024] float4
    const float* __restrict__ B,     // [4096][16]
    const float* __restrict__ mag,   // [4096]
    unsigned short* __restrict__ wbf,
    float* __restrict__ scale) {
    const int tid = threadIdx.x;
    const int m0 = blockIdx.x * 4;
    __shared__ float4 Bsh4[4][4];    // 4 rows x 16 floats
    __shared__ float red[16];
    if (tid < 64) ((float*)Bsh4)[tid] = B[m0 * 16 + tid];
    __syncthreads();
    float ss[4] = {};
    for (int c = tid; c < 1024; c += 256) {   // 4 iters
        float4 w[4];
#pragma unroll
        for (int i = 0; i < 4; ++i) w[i] = W4[(size_t)(m0 + i) * 1024 + c];
#pragma unroll
        for (int rg = 0; rg < 4; ++rg) {
            float4 a[4];
#pragma unroll
            for (int r = 0; r < 4; ++r) a[r] = A4[(rg * 4 + r) * 1024 + c];
#pragma unroll
            for (int i = 0; i < 4; ++i) {
                const float4 b = Bsh4[i][rg];
                w[i].x += b.x * a[0].x + b.y * a[1].x + b.z * a[2].x + b.w * a[3].x;
                w[i].y += b.x * a[0].y + b.y * a[1].y + b.z * a[2].y + b.w * a[3].y;
                w[i].z += b.x * a[0].z + b.y * a[1].z + b.z * a[2].z + b.w * a[3].z;
                w[i].w += b.x * a[0].w + b.y * a[1].w + b.z * a[2].w + b.w * a[3].w;
            }
        }
#pragma unroll
        for (int i = 0; i < 4; ++i) {
            ss[i] += w[i].x * w[i].x + w[i].y * w[i].y + w[i].z * w[i].z + w[i].w * w[i].w;
            us4 o; o[0] = bf_rne(w[i].x); o[1] = bf_rne(w[i].y);
            o[2] = bf_rne(w[i].z); o[3] = bf_rne(w[i].w);
            *(us4*)&wbf[(size_t)(m0 + i) * 4096 + c * 4] = o;
        }
    }
    const int lane = tid & 63, wv = tid >> 6;
#pragma unroll
    for (int i = 0; i < 4; ++i) {
        float v = ss[i];
#pragma unroll
        for (int off = 32; off > 0; off >>= 1) v += __shfl_down(v, off, 64);
        if (lane == 0) red[wv * 4 + i] = v;
    }
    __syncthreads();
    if (tid < 4) {
        float tot = red[tid] + red[4 + tid] + red[8 + tid] + red[12 + tid];
        scale[m0 + tid] = mag[m0 + tid] / sqrtf(tot);
    }
}

// ---------------- cvt: x fp32 -> bf16, unit-stride float4 -> us4 (8B) ----------------
__global__ __launch_bounds__(256) void cvt_kernel(
    const float4* __restrict__ x4, us4* __restrict__ xbf4) {
    const size_t base = (size_t)blockIdx.x * 1024 + threadIdx.x;
#pragma unroll
    for (int j = 0; j < 4; ++j) {
        const size_t idx = base + j * 256;
        float4 a = x4[idx];
        us4 o;
        o[0] = bf_rne(a.x); o[1] = bf_rne(a.y);
        o[2] = bf_rne(a.z); o[3] = bf_rne(a.w);
        xbf4[idx] = o;
    }
}

// ---------------- GEMM: C[8192][4096] = xbf @ wbf^T * scale ----------------
// 256x256 tile, BK=64, 8 waves (2M x 4N), 32x32x16 MFMA, kc-clustered software
// pipeline with counted lgkmcnt (operands for cluster k+1 in flight during
// cluster k's MFMAs). ONE barrier + one amply-covered vmcnt(0) per K-tile.
// Hazards: stages at tile-u start write buf[~cur]; tile u-1's reads of that
// buffer retired before each wave's last cluster (lgkm waits) and all waves
// passed BAR_end(u-1) => safe. ops0(u) reads buf[cur], landed via tile-(u-1)'s
// per-wave vmcnt(0) before BAR_end(u-1) => safe.
__global__ __launch_bounds__(512, 2) void dora_gemm(
    const unsigned short* __restrict__ xbf,   // [8192][4096] bf16
    const unsigned short* __restrict__ wbf,   // [4096][4096] bf16
    const float* __restrict__ scale,          // [4096]
    float* __restrict__ out) {                // [8192][4096] fp32
    constexpr int TSZ = 256 * 64;             // shorts per K-tile buffer (32 KiB)
    __shared__ __align__(16) unsigned short As[2 * TSZ];
    __shared__ __align__(16) unsigned short Bs[2 * TSZ];

    const int tid  = threadIdx.x;
    const int lane = tid & 63;
    const int w    = tid >> 6;     // wave 0..7
    const int wm   = w >> 2;       // 0..1  (M half: 128 rows)
    const int wn   = w & 3;        // 0..3  (N quarter: 64 cols)
    const int l31  = lane & 31;
    const int hi   = lane >> 5;    // k-half selector for 32x32x16 frags

    // bijective XCD-chunked swizzle: 512 blocks = 8 XCDs x 64; N-fast within XCD
    const int L = (blockIdx.x & 7) * 64 + (blockIdx.x >> 3);
    const int tileM = (L >> 4) * 256;   // 32 M-tiles
    const int tileN = (L & 15) * 256;   // 16 N-tiles

    // staging: XOR swizzle, physical 16B chunk p of row r holds logical p ^ (r&7)
    const int i8 = lane >> 3;
    const int lc = (lane & 7) ^ i8;     // pre-swizzled global source chunk

    const unsigned short* gA = xbf + (size_t)tileM * 4096;
    const unsigned short* gB = wbf + (size_t)tileN * 4096;

    auto stage = [&](const unsigned short* __restrict__ g,
                     unsigned short* lbase, int T, int h) {
#pragma unroll
        for (int j = 0; j < 2; ++j) {
            const int r0 = h * 128 + w * 16 + j * 8;   // wave-uniform
            GLD_LDS16(g + (size_t)(r0 + i8) * 4096 + T * 64 + lc * 8,
                      lbase + r0 * 64);
        }
    };

    f32x16 acc[4][2] = {};   // 4 mt x 2 nt 32x32 frags = wave tile 128x64

    // issue one kc-slice's operands (6 x ds_read_b128): af row=..+l31,
    // chunk = 2*kc + hi, phys = chunk ^ (row&7)
    auto ops_issue = [&](int kc, s16x8 (&af)[4], s16x8 (&bf)[2],
                         const unsigned short* Ac, const unsigned short* Bc) {
#pragma unroll
        for (int mt = 0; mt < 4; ++mt) {
            const int row = wm * 128 + mt * 32 + l31;
            af[mt] = *(const s16x8*)&Ac[row * 64 + ((2 * kc + hi) ^ (row & 7)) * 8];
        }
#pragma unroll
        for (int nt = 0; nt < 2; ++nt) {
            const int row = wn * 64 + nt * 32 + l31;
            bf[nt] = *(const s16x8*)&Bc[row * 64 + ((2 * kc + hi) ^ (row & 7)) * 8];
        }
    };

    auto cluster = [&](s16x8 (&af)[4], s16x8 (&bf)[2]) {
        __builtin_amdgcn_s_setprio(1);
#pragma unroll
        for (int mt = 0; mt < 4; ++mt)
#pragma unroll
            for (int nt = 0; nt < 2; ++nt)
                acc[mt][nt] = __builtin_amdgcn_mfma_f32_32x32x16_bf16(
                    af[mt], bf[nt], acc[mt][nt], 0, 0, 0);
        __builtin_amdgcn_s_setprio(0);
    };

    // pipeline prologue: tile0 -> buf0
    stage(gA, As, 0, 0); stage(gA, As, 0, 1);
    stage(gB, Bs, 0, 0); stage(gB, Bs, 0, 1);
    VMC(0);
    __builtin_amdgcn_s_barrier();

    s16x8 afA[4], bfA[2], afB[4], bfB[2];

    for (int t = 0; t < 64; ++t) {
        const int cur = t & 1;
        const unsigned short* Ac = As + cur * TSZ;
        const unsigned short* Bc = Bs + cur * TSZ;
        unsigned short* An = As + (cur ^ 1) * TSZ;
        unsigned short* Bn = Bs + (cur ^ 1) * TSZ;

        ops_issue(0, afA, bfA, Ac, Bc);                 // kc0 operands
        if (t < 63) {                                   // next-tile staging (8 gld)
            stage(gA, An, t + 1, 0); stage(gA, An, t + 1, 1);
            stage(gB, Bn, t + 1, 0); stage(gB, Bn, t + 1, 1);
        }
        ops_issue(1, afB, bfB, Ac, Bc);                 // kc1 in flight
        LGKM(6); SFENCE();                              // kc0 ready, kc1 flying
        cluster(afA, bfA);                              // kc0
        ops_issue(2, afA, bfA, Ac, Bc);                 // kc2 in flight
        LGKM(6); SFENCE();                              // kc1 ready
        cluster(afB, bfB);                              // kc1
        ops_issue(3, afB, bfB, Ac, Bc);                 // kc3 in flight
        LGKM(6); SFENCE();                              // kc2 ready
        cluster(afA, bfA);                              // kc2
        LGKM(0); SFENCE();                              // kc3 ready
        cluster(afB, bfB);                              // kc3
        if (t < 63) VMC(0);                             // stages landed (~full-tile cover)
        __builtin_amdgcn_s_barrier();
    }

    // epilogue: 32x32 C/D layout col=lane&31, row=(r&3)+8*(r>>2)+4*(lane>>5)
#pragma unroll
    for (int nt = 0; nt < 2; ++nt) {
        const int col = tileN + wn * 64 + nt * 32 + l31;
        const float s = scale[col];
#pragma unroll
        for (int mt = 0; mt < 4; ++mt) {
            const int rbase = tileM + wm * 128 + mt * 32 + hi * 4;
#pragma unroll
            for (int r = 0; r < 16; ++r) {
                const int row = rbase + (r & 3) + 8 * (r >> 2);
                out[(size_t)row * 4096 + col] = acc[mt][nt][r] * s;
            }
        }
    }
}

extern "C" void kernel_launch(void* const* d_in, const int* in_sizes, int n_in,
                              void* d_out, int out_size, void* d_ws, size_t ws_size,
                              hipStream_t stream) {
    const float* x   = (const float*)d_in[0];   // [4,2048,4096]
    const float* W   = (const float*)d_in[1];   // [4096,4096]
    const float* A   = (const float*)d_in[2];   // [16,4096]
    const float* B   = (const float*)d_in[3];   // [4096,16]
    const float* mag = (const float*)d_in[4];   // [4096]
    float* out = (float*)d_out;

    const size_t XBF_BYTES = (size_t)8192 * 4096 * 2;  // 67,108,864
    const size_t WBF_BYTES = (size_t)4096 * 4096 * 2;  // 33,554,432
    const size_t NEEDED = XBF_BYTES + WBF_BYTES + 4096 * sizeof(float);
    if (ws_size < NEEDED) return;

    unsigned short* xbf = (unsigned short*)d_ws;
    unsigned short* wbf = (unsigned short*)((char*)d_ws + XBF_BYTES);
    float* scale = (float*)((char*)d_ws + XBF_BYTES + WBF_BYTES);

    cvt_kernel<<<8192, 256, 0, stream>>>((const float4*)x, (us4*)xbf);
    prep_kernel<<<1024, 256, 0, stream>>>((const float4*)W, (const float4*)A,
                                          B, mag, wbf, scale);
    dora_gemm<<<512, 512, 0, stream>>>(xbf, wbf, scale, out);
}